// Round 11
// baseline (4763.607 us; speedup 1.0000x reference)
//
#include <hip/hip_runtime.h>

#define SEQL   512
#define HID    2048
#define NCLS   10

typedef _Float16 f16x8 __attribute__((ext_vector_type(8)));
typedef float    f32x4 __attribute__((ext_vector_type(4)));
typedef unsigned uintx4 __attribute__((ext_vector_type(4)));

__device__ __forceinline__ float fast_tanh(float v) {
    float e = __expf(2.0f * v);
    return 1.0f - 2.0f / (e + 1.0f);
}

// Pack whh (fp32 row-major [col][k]) into fp16 MFMA fragments, two regions:
//   P [0,4MiB):  member-major pinned cols [colbase, colbase+32), all K -> LDS
//   R [4MiB,8MiB): per-wave pinned cols [colbase+32, colbase+64):
//     wave j holds col-block cbb=j&1 (16 cols), kst-quarter kq=j>>1 (16 ksts)
__global__ void pack_w_kernel(const float* __restrict__ w, _Float16* __restrict__ o) {
    const int fid = blockIdx.x * 256 + threadIdx.x;   // 0..524287
    int col, k0;
    if (fid < 262144) {                 // P: m(5b) | tile(1b) | kst(6b) | ln(6b)
        const int m = fid >> 13, s5 = fid & 8191;
        const int tile = s5 >> 12, kst = (s5 >> 6) & 63, ln = s5 & 63;
        col = m * 64 + tile * 16 + (ln & 15);
        k0  = kst * 32 + (ln >> 4) * 8;
    } else {                            // R: m(5b) | j(3b) | f(4b) | ln(6b)
        const int q = fid - 262144;
        const int m = q >> 13, r = q & 8191;
        const int j = r >> 10, f = (r >> 6) & 15, ln = r & 63;
        col = m * 64 + 32 + (j & 1) * 16 + (ln & 15);
        k0  = ((j >> 1) * 16 + f) * 32 + (ln >> 4) * 8;
    }
    const float* src = w + (size_t)col * HID + k0;
    f16x8 v;
    #pragma unroll
    for (int i = 0; i < 8; ++i) v[i] = (_Float16)src[i];
    *(f16x8*)(o + (size_t)fid * 8) = v;
}

__global__ void __launch_bounds__(512, 2)
rnn_main(const float* __restrict__ x, const float* __restrict__ whx,
         const _Float16* __restrict__ Wp, const float* __restrict__ bh,
         const float* __restrict__ wph, const float* __restrict__ bp,
         _Float16* __restrict__ h0, _Float16* __restrict__ h1,
         unsigned* __restrict__ ctr, float* __restrict__ out)
{
    // 128 KiB pinned W cols [colbase,colbase+32): slot(tile,kst,lane)
    __shared__ uint4 ldsW[8192];
    // 16 KiB partial-reduce buffer: 16 slots x 64 lanes x f32x4
    __shared__ f32x4 ldsR[16 * 64];

    const int tid = threadIdx.x;

    // physical XCD id -> group; member slot via allocator (32 WGs/XCD: 1 WG/CU)
    int xcc;
    asm volatile("s_getreg_b32 %0, hwreg(HW_REG_XCC_ID)" : "=s"(xcc));
    const int g = xcc & 7;
    unsigned* alloc   = ctr + g * 64;
    unsigned* flgbase = ctr + 512 + g * 1024;      // 32 member flags, 128B stride
    if (tid == 0) {
        unsigned s = __hip_atomic_fetch_add(alloc, 1u, __ATOMIC_RELAXED, __HIP_MEMORY_SCOPE_WORKGROUP);
        ((unsigned*)ldsR)[0] = s;
    }
    __syncthreads();
    const int m = (int)((unsigned*)ldsR)[0];       // 0..31 (ldsR reused later)
    unsigned* myflg = flgbase + m * 32;
    const int rowbase = g * 32;
    const int colbase = m * 64;

    const int lane = tid & 63;
    const int j    = tid >> 6;        // wave 0..7
    const int cbb  = j & 1;           // col-16-block (both classes)
    const int kq   = j >> 1;          // kst quarter 0..3

    const uint4* P4 = (const uint4*)Wp;

    // ---- pin P (cols colbase..+32) into LDS ----
    for (int s5 = tid; s5 < 8192; s5 += 512)
        ldsW[s5] = P4[m * 8192 + s5];

    // ---- step 0: h = tanh(x[:,0]*whx + bh) ----
    for (int i = tid; i < 32 * 64; i += 512) {
        const int r = i >> 6, c = i & 63;
        const int b = rowbase + r, jj = colbase + c;
        h0[(size_t)b * HID + jj] = (_Float16)fast_tanh(x[(size_t)b * SEQL] * whx[jj] + bh[jj]);
    }

    // ---- pin this wave's 16 R-frags (64 VGPR) for all 512 steps ----
    const uint4* R4 = P4 + 262144 + m * 8192 + j * 1024 + lane;
    f16x8 bR[16];
    #pragma unroll
    for (int f = 0; f < 16; ++f) bR[f] = *(const f16x8*)&R4[f * 64];

    // epilogue tile owned by this wave: (wm=j>>2, class=(j>>1)&1, cb=j&1)
    const int ecls = (j >> 1) & 1, ewm = j >> 2;
    const int ecol = colbase + ecls * 32 + cbb * 16 + (lane & 15);
    const float wxc = whx[ecol], bbc = bh[ecol];
    const int erow = rowbase + ewm * 16 + (lane >> 4) * 4;
    const int rdbase = ecls * 8 + cbb * 4;

    // A-fragment source geometry (rows via lane&15, k via lane>>4 and kq)
    const size_t aoff = (size_t)(rowbase + (lane & 15)) * HID + (lane >> 4) * 8 + kq * 16 * 32;
    const uint4* bl = &ldsW[cbb * 4096 + kq * 16 * 64 + lane];
    const unsigned* pollp = flgbase + (lane & 31) * 32;

    // arrive for step 0 (syncthreads drains all h-stores first)
    __syncthreads();
    if (tid == 0)
        __hip_atomic_fetch_add(myflg, 1u, __ATOMIC_RELAXED, __HIP_MEMORY_SCOPE_WORKGROUP);

    for (int t = 1; t < SEQL; ++t) {
        const _Float16* hs = (t & 1) ? h0 : h1;
        _Float16*       hd = (t & 1) ? h1 : h0;
        const _Float16* ap  = hs + aoff;
        const _Float16* ap1 = ap + 16 * HID;

        // keep reg-pinned fragments materialized
        #pragma unroll
        for (int f = 0; f < 16; ++f) asm volatile("" : "+v"(bR[f]));

        // epilogue x-values: stale-safe input, issue before the poll
        float xv[4];
        #pragma unroll
        for (int r = 0; r < 4; ++r)
            xv[r] = x[(size_t)(erow + r) * SEQL + t];

        // per-wave poll: all 8 waves watch the 32 member flags (agent scope =
        // L1-bypass, served by local L2); no release syncthreads needed
        {
            unsigned v;
            do {
                v = __hip_atomic_load(pollp, __ATOMIC_RELAXED, __HIP_MEMORY_SCOPE_AGENT);
            } while (!__all((int)(v >= (unsigned)t)));
        }
        asm volatile("buffer_inv sc0" ::: "memory");   // this CU's L1 -> fresh h via L2

        // forced A-burst: 32 volatile asm loads issue back-to-back (cannot be
        // sunk by the compiler), one drain, then MFMAs. ~1 L2 latency total.
        uintx4 av0[16], av1[16];
        #pragma unroll
        for (int f = 0; f < 16; ++f) {
            asm volatile("global_load_dwordx4 %0, %1, off"
                         : "=v"(av0[f]) : "v"(ap + f * 32));
            asm volatile("global_load_dwordx4 %0, %1, off"
                         : "=v"(av1[f]) : "v"(ap1 + f * 32));
        }
        asm volatile("s_waitcnt vmcnt(0)" ::: "memory");
        __builtin_amdgcn_sched_barrier(0);             // rule #18: pin MFMAs after the wait

        f32x4 aL0 = {0.f,0.f,0.f,0.f}, aL1 = aL0, aR0 = aL0, aR1 = aL0;

        // 16 k-steps, 4 independent MFMA chains; B from LDS / pinned regs
        #pragma unroll
        for (int f = 0; f < 16; ++f) {
            const f16x8 a0 = __builtin_bit_cast(f16x8, av0[f]);
            const f16x8 a1 = __builtin_bit_cast(f16x8, av1[f]);
            const f16x8 bLf = *(const f16x8*)&bl[f * 64];
            aL0 = __builtin_amdgcn_mfma_f32_16x16x32_f16(a0, bLf,   aL0, 0, 0, 0);
            aL1 = __builtin_amdgcn_mfma_f32_16x16x32_f16(a1, bLf,   aL1, 0, 0, 0);
            aR0 = __builtin_amdgcn_mfma_f32_16x16x32_f16(a0, bR[f], aR0, 0, 0, 0);
            aR1 = __builtin_amdgcn_mfma_f32_16x16x32_f16(a1, bR[f], aR1, 0, 0, 0);
        }

        // ---- phase 0 (wm=0 tiles): write partials, sum by waves 0..3 ----
        ldsR[(cbb * 4 + kq) * 64 + lane]       = aL0;
        ldsR[(8 + cbb * 4 + kq) * 64 + lane]   = aR0;
        __syncthreads();
        if (j < 4) {
            const f32x4 s = ldsR[(rdbase + 0) * 64 + lane] + ldsR[(rdbase + 1) * 64 + lane]
                          + ldsR[(rdbase + 2) * 64 + lane] + ldsR[(rdbase + 3) * 64 + lane];
            #pragma unroll
            for (int r = 0; r < 4; ++r) {
                const int br = erow + r;
                hd[(size_t)br * HID + ecol] =
                    (_Float16)fast_tanh(s[r] + xv[r] * wxc + bbc);
            }
        }
        __syncthreads();
        // ---- phase 1 (wm=1 tiles): write partials, sum by waves 4..7 ----
        ldsR[(cbb * 4 + kq) * 64 + lane]       = aL1;
        ldsR[(8 + cbb * 4 + kq) * 64 + lane]   = aR1;
        __syncthreads();
        if (j >= 4) {
            const f32x4 s = ldsR[(rdbase + 0) * 64 + lane] + ldsR[(rdbase + 1) * 64 + lane]
                          + ldsR[(rdbase + 2) * 64 + lane] + ldsR[(rdbase + 3) * 64 + lane];
            #pragma unroll
            for (int r = 0; r < 4; ++r) {
                const int br = erow + r;
                hd[(size_t)br * HID + ecol] =
                    (_Float16)fast_tanh(s[r] + xv[r] * wxc + bbc);
            }
        }

        // arrive: syncthreads drains every wave's h-stores (vmcnt(0)) first
        __syncthreads();
        if (tid == 0)
            __hip_atomic_fetch_add(myflg, 1u, __ATOMIC_RELAXED, __HIP_MEMORY_SCOPE_WORKGROUP);
    }

    // final release before projection (all waves poll, then L1 inv)
    {
        unsigned v;
        do {
            v = __hip_atomic_load(pollp, __ATOMIC_RELAXED, __HIP_MEMORY_SCOPE_AGENT);
        } while (!__all((int)(v >= (unsigned)SEQL)));
    }
    asm volatile("buffer_inv sc0" ::: "memory");

    // ---- projection: p = h_last @ wph.T + bp (member m -> row rowbase+m) ----
    const int brow = rowbase + m;
    const _Float16* hp = h1 + (size_t)brow * HID + lane * 32;
    for (int c = j; c < NCLS; c += 8) {
        const float* wp = wph + (size_t)c * HID + lane * 32;
        float psum = 0.f;
        #pragma unroll
        for (int i = 0; i < 32; ++i) psum += (float)hp[i] * wp[i];
        #pragma unroll
        for (int off = 32; off >= 1; off >>= 1) psum += __shfl_xor(psum, off, 64);
        if (lane == 0) out[brow * NCLS + c] = psum + bp[c];
    }
}

extern "C" void kernel_launch(void* const* d_in, const int* in_sizes, int n_in,
                              void* d_out, int out_size, void* d_ws, size_t ws_size,
                              hipStream_t stream) {
    const float* x   = (const float*)d_in[0];
    const float* whx = (const float*)d_in[1];
    const float* whh = (const float*)d_in[2];
    const float* bh  = (const float*)d_in[3];
    const float* wph = (const float*)d_in[4];
    const float* bp  = (const float*)d_in[5];
    float* out = (float*)d_out;

    char* ws = (char*)d_ws;
    _Float16* Wp  = (_Float16*)ws;                         // 8 MiB packed whh fp16 (P + R)
    _Float16* h0  = (_Float16*)(ws + (size_t)(8u << 20));  // 1 MiB  h buffer A
    _Float16* h1  = (_Float16*)(ws + (size_t)(9u << 20));  // 1 MiB  h buffer B
    unsigned* ctr = (unsigned*)(ws + (size_t)(10u << 20)); // 36 KiB alloc + flags

    hipMemsetAsync(ctr, 0, (512 + 8 * 1024) * sizeof(unsigned), stream);
    pack_w_kernel<<<dim3(2048), dim3(256), 0, stream>>>(whh, Wp);

    void* args[] = { (void*)&x, (void*)&whx, (void*)&Wp, (void*)&bh, (void*)&wph,
                     (void*)&bp, (void*)&h0, (void*)&h1, (void*)&ctr, (void*)&out };
    hipLaunchCooperativeKernel((const void*)rnn_main, dim3(256), dim3(512),
                               args, 0, stream);
}

// Round 12
// 4380.939 us; speedup vs baseline: 1.0873x; 1.0873x over previous
//
#include <hip/hip_runtime.h>

#define SEQL   512
#define HID    2048
#define NCLS   10

typedef _Float16 f16x8 __attribute__((ext_vector_type(8)));
typedef float    f32x4 __attribute__((ext_vector_type(4)));

__device__ __forceinline__ float fast_tanh(float v) {
    float e = __expf(2.0f * v);
    return 1.0f - 2.0f / (e + 1.0f);
}

// Pack whh (fp32 row-major [col][k]) into fp16 MFMA fragments, two regions:
//   P [0,4MiB):  member-major pinned cols [colbase, colbase+32), all K -> LDS
//   R [4MiB,8MiB): per-wave pinned cols [colbase+32, colbase+64):
//     wave j holds col-block cbb=j&1 (16 cols), kst-quarter kq=j>>1 (16 ksts)
__global__ void pack_w_kernel(const float* __restrict__ w, _Float16* __restrict__ o) {
    const int fid = blockIdx.x * 256 + threadIdx.x;   // 0..524287
    int col, k0;
    if (fid < 262144) {                 // P: m(5b) | tile(1b) | kst(6b) | ln(6b)
        const int m = fid >> 13, s5 = fid & 8191;
        const int tile = s5 >> 12, kst = (s5 >> 6) & 63, ln = s5 & 63;
        col = m * 64 + tile * 16 + (ln & 15);
        k0  = kst * 32 + (ln >> 4) * 8;
    } else {                            // R: m(5b) | j(3b) | f(4b) | ln(6b)
        const int q = fid - 262144;
        const int m = q >> 13, r = q & 8191;
        const int j = r >> 10, f = (r >> 6) & 15, ln = r & 63;
        col = m * 64 + 32 + (j & 1) * 16 + (ln & 15);
        k0  = ((j >> 1) * 16 + f) * 32 + (ln >> 4) * 8;
    }
    const float* src = w + (size_t)col * HID + k0;
    f16x8 v;
    #pragma unroll
    for (int i = 0; i < 8; ++i) v[i] = (_Float16)src[i];
    *(f16x8*)(o + (size_t)fid * 8) = v;
}

__global__ void __launch_bounds__(512, 2)
rnn_main(const float* __restrict__ x, const float* __restrict__ whx,
         const _Float16* __restrict__ Wp, const float* __restrict__ bh,
         const float* __restrict__ wph, const float* __restrict__ bp,
         _Float16* __restrict__ h0, _Float16* __restrict__ h1,
         unsigned* __restrict__ ctr, float* __restrict__ out)
{
    // 128 KiB pinned W cols [colbase,colbase+32): slot(tile,kst,lane)
    __shared__ uint4 ldsW[8192];
    // 16 KiB partial buffer: slot = (tile tj 0..3)*4 + kq, tj = ecls*2 + ecbb
    __shared__ f32x4 ldsR[16 * 64];
    __shared__ unsigned s_mslot;

    const int tid = threadIdx.x;

    // physical XCD id -> group; member slot via allocator (32 WGs/XCD: 1 WG/CU)
    int xcc;
    asm volatile("s_getreg_b32 %0, hwreg(HW_REG_XCC_ID)" : "=s"(xcc));
    const int g = xcc & 7;
    unsigned* alloc = ctr + g * 64;
    unsigned* flgA  = ctr + 512 + g * 1024;           // 32 member flags, 128B stride
    unsigned* flgB  = ctr + 512 + 8192 + g * 1024;    // sub-batch B flags
    if (tid == 0)
        s_mslot = __hip_atomic_fetch_add(alloc, 1u, __ATOMIC_RELAXED, __HIP_MEMORY_SCOPE_WORKGROUP);
    __syncthreads();
    const int m = (int)s_mslot;              // 0..31
    unsigned* myflgA = flgA + m * 32;
    unsigned* myflgB = flgB + m * 32;
    const int rowbase = g * 32;              // rows [rowbase,+16)=A, [+16,+32)=B
    const int colbase = m * 64;

    const int lane = tid & 63;
    const int j    = tid >> 6;        // wave 0..7
    const int cbb  = j & 1;           // col-16-block (both classes)
    const int kq   = j >> 1;          // kst quarter 0..3

    const uint4* P4 = (const uint4*)Wp;

    // ---- pin P (cols colbase..+32) into LDS ----
    for (int s5 = tid; s5 < 8192; s5 += 512)
        ldsW[s5] = P4[m * 8192 + s5];

    // ---- step 0: h = tanh(x[:,0]*whx + bh) for all 32 rows ----
    for (int i = tid; i < 32 * 64; i += 512) {
        const int r = i >> 6, c = i & 63;
        const int b = rowbase + r, jj = colbase + c;
        h0[(size_t)b * HID + jj] = (_Float16)fast_tanh(x[(size_t)b * SEQL] * whx[jj] + bh[jj]);
    }

    // ---- pin this wave's 16 R-frags (64 VGPR) for all 512 steps ----
    const uint4* R4 = P4 + 262144 + m * 8192 + j * 1024 + lane;
    f16x8 bR[16];
    #pragma unroll
    for (int f = 0; f < 16; ++f) bR[f] = *(const f16x8*)&R4[f * 64];

    // reducer role: waves 0..3 own sub-batch A epilogue, 4..7 own B
    const int tj   = (j < 4) ? j : j - 4;          // tile 0..3 = ecls*2 + ecbb
    const int ecls = tj >> 1, ecbb = tj & 1;
    const int ecol = colbase + ecls * 32 + ecbb * 16 + (lane & 15);
    const float wxc = whx[ecol], bbc = bh[ecol];
    const int eroff = (lane >> 4) * 4;             // + sub_rowbase + r
    const int rdbase = tj * 4;

    // A-operand geometry: row = sub_rowbase + (lane&15), k = kq*512 + f*32 + (lane>>4)*8
    const size_t aoffA = (size_t)(rowbase + (lane & 15)) * HID + kq * 512 + (lane >> 4) * 8;
    const size_t aoffB = aoffA + (size_t)16 * HID;
    const uint4* bl = &ldsW[cbb * 4096 + kq * 1024 + lane];
    const unsigned* pollA = flgA + (lane & 31) * 32;
    const unsigned* pollB = flgB + (lane & 31) * 32;

    // prologue arrive: syncthreads drains all step-0 h stores, then post both flags
    __syncthreads();
    if (tid == 0) {
        __hip_atomic_fetch_add(myflgA, 4u, __ATOMIC_RELAXED, __HIP_MEMORY_SCOPE_WORKGROUP);
        __hip_atomic_fetch_add(myflgB, 4u, __ATOMIC_RELAXED, __HIP_MEMORY_SCOPE_WORKGROUP);
    }

    for (int t = 1; t < SEQL; ++t) {
        const _Float16* hs = (t & 1) ? h0 : h1;
        _Float16*       hd = (t & 1) ? h1 : h0;
        const unsigned tgt = 4u * (unsigned)t;

        // keep reg-pinned fragments materialized
        #pragma unroll
        for (int f = 0; f < 16; ++f) asm volatile("" : "+v"(bR[f]));

        // ================= sub-step A (rows rowbase..+16, reducers j<4) ======
        {
            float xv[4];
            if (j < 4) {
                #pragma unroll
                for (int r = 0; r < 4; ++r)
                    xv[r] = x[(size_t)(rowbase + eroff + r) * SEQL + t];
            }
            // poll A flags (agent scope = L1-bypass, local-L2 read)
            unsigned v;
            do {
                v = __hip_atomic_load(pollA, __ATOMIC_RELAXED, __HIP_MEMORY_SCOPE_AGENT);
            } while (!__all((int)(v >= tgt)));
            asm volatile("buffer_inv sc0" ::: "memory");   // fresh h via L2

            f16x8 av[16];
            #pragma unroll
            for (int f = 0; f < 16; ++f)
                av[f] = *(const f16x8*)(hs + aoffA + f * 32);

            f32x4 aL = {0.f,0.f,0.f,0.f}, aR = aL;
            #pragma unroll
            for (int f = 0; f < 16; ++f) {
                const f16x8 bLf = *(const f16x8*)&bl[f * 64];
                aL = __builtin_amdgcn_mfma_f32_16x16x32_f16(av[f], bLf,   aL, 0, 0, 0);
                aR = __builtin_amdgcn_mfma_f32_16x16x32_f16(av[f], bR[f], aR, 0, 0, 0);
            }

            __syncthreads();   // prior sub-step's ldsR readers done
            ldsR[(cbb * 4 + kq) * 64 + lane]       = aL;   // L tiles: tj = cbb
            ldsR[((2 + cbb) * 4 + kq) * 64 + lane] = aR;   // R tiles: tj = 2+cbb
            __syncthreads();

            if (j < 4) {
                const f32x4 s = ldsR[(rdbase + 0) * 64 + lane] + ldsR[(rdbase + 1) * 64 + lane]
                              + ldsR[(rdbase + 2) * 64 + lane] + ldsR[(rdbase + 3) * 64 + lane];
                #pragma unroll
                for (int r = 0; r < 4; ++r) {
                    const int br = rowbase + eroff + r;
                    hd[(size_t)br * HID + ecol] =
                        (_Float16)fast_tanh(s[r] + xv[r] * wxc + bbc);
                }
                asm volatile("s_waitcnt vmcnt(0)" ::: "memory");  // wave's stores at L2
                if (lane == 0)
                    __hip_atomic_fetch_add(myflgA, 1u, __ATOMIC_RELAXED, __HIP_MEMORY_SCOPE_WORKGROUP);
            }
        }

        // ================= sub-step B (rows rowbase+16..+32, reducers j>=4) ==
        {
            float xv[4];
            if (j >= 4) {
                #pragma unroll
                for (int r = 0; r < 4; ++r)
                    xv[r] = x[(size_t)(rowbase + 16 + eroff + r) * SEQL + t];
            }
            unsigned v;
            do {
                v = __hip_atomic_load(pollB, __ATOMIC_RELAXED, __HIP_MEMORY_SCOPE_AGENT);
            } while (!__all((int)(v >= tgt)));
            asm volatile("buffer_inv sc0" ::: "memory");

            f16x8 av[16];
            #pragma unroll
            for (int f = 0; f < 16; ++f)
                av[f] = *(const f16x8*)(hs + aoffB + f * 32);

            f32x4 aL = {0.f,0.f,0.f,0.f}, aR = aL;
            #pragma unroll
            for (int f = 0; f < 16; ++f) {
                const f16x8 bLf = *(const f16x8*)&bl[f * 64];
                aL = __builtin_amdgcn_mfma_f32_16x16x32_f16(av[f], bLf,   aL, 0, 0, 0);
                aR = __builtin_amdgcn_mfma_f32_16x16x32_f16(av[f], bR[f], aR, 0, 0, 0);
            }

            __syncthreads();
            ldsR[(cbb * 4 + kq) * 64 + lane]       = aL;
            ldsR[((2 + cbb) * 4 + kq) * 64 + lane] = aR;
            __syncthreads();

            if (j >= 4) {
                const f32x4 s = ldsR[(rdbase + 0) * 64 + lane] + ldsR[(rdbase + 1) * 64 + lane]
                              + ldsR[(rdbase + 2) * 64 + lane] + ldsR[(rdbase + 3) * 64 + lane];
                #pragma unroll
                for (int r = 0; r < 4; ++r) {
                    const int br = rowbase + 16 + eroff + r;
                    hd[(size_t)br * HID + ecol] =
                        (_Float16)fast_tanh(s[r] + xv[r] * wxc + bbc);
                }
                asm volatile("s_waitcnt vmcnt(0)" ::: "memory");
                if (lane == 0)
                    __hip_atomic_fetch_add(myflgB, 1u, __ATOMIC_RELAXED, __HIP_MEMORY_SCOPE_WORKGROUP);
            }
        }
    }

    // final release: both sub-batches' t=511 stores visible, then L1 inv
    {
        const unsigned tgt = 4u * (unsigned)SEQL;
        unsigned v;
        do {
            v = __hip_atomic_load(pollA, __ATOMIC_RELAXED, __HIP_MEMORY_SCOPE_AGENT);
        } while (!__all((int)(v >= tgt)));
        do {
            v = __hip_atomic_load(pollB, __ATOMIC_RELAXED, __HIP_MEMORY_SCOPE_AGENT);
        } while (!__all((int)(v >= tgt)));
    }
    asm volatile("buffer_inv sc0" ::: "memory");

    // ---- projection: p = h_last @ wph.T + bp (member m -> row rowbase+m) ----
    const int brow = rowbase + m;
    const _Float16* hp = h1 + (size_t)brow * HID + lane * 32;
    for (int c = j; c < NCLS; c += 8) {
        const float* wp = wph + (size_t)c * HID + lane * 32;
        float psum = 0.f;
        #pragma unroll
        for (int i = 0; i < 32; ++i) psum += (float)hp[i] * wp[i];
        #pragma unroll
        for (int off = 32; off >= 1; off >>= 1) psum += __shfl_xor(psum, off, 64);
        if (lane == 0) out[brow * NCLS + c] = psum + bp[c];
    }
}

extern "C" void kernel_launch(void* const* d_in, const int* in_sizes, int n_in,
                              void* d_out, int out_size, void* d_ws, size_t ws_size,
                              hipStream_t stream) {
    const float* x   = (const float*)d_in[0];
    const float* whx = (const float*)d_in[1];
    const float* whh = (const float*)d_in[2];
    const float* bh  = (const float*)d_in[3];
    const float* wph = (const float*)d_in[4];
    const float* bp  = (const float*)d_in[5];
    float* out = (float*)d_out;

    char* ws = (char*)d_ws;
    _Float16* Wp  = (_Float16*)ws;                         // 8 MiB packed whh fp16 (P + R)
    _Float16* h0  = (_Float16*)(ws + (size_t)(8u << 20));  // 1 MiB  h buffer A
    _Float16* h1  = (_Float16*)(ws + (size_t)(9u << 20));  // 1 MiB  h buffer B
    unsigned* ctr = (unsigned*)(ws + (size_t)(10u << 20)); // 68 KiB alloc + 2x flags

    hipMemsetAsync(ctr, 0, (512 + 2 * 8 * 1024) * sizeof(unsigned), stream);
    pack_w_kernel<<<dim3(2048), dim3(256), 0, stream>>>(whh, Wp);

    void* args[] = { (void*)&x, (void*)&whx, (void*)&Wp, (void*)&bh, (void*)&wph,
                     (void*)&bp, (void*)&h0, (void*)&h1, (void*)&ctr, (void*)&out };
    hipLaunchCooperativeKernel((const void*)rnn_main, dim3(256), dim3(512),
                               args, 0, stream);
}